// Round 2
// baseline (237.488 us; speedup 1.0000x reference)
//
#include <hip/hip_runtime.h>
#include <hip/hip_bf16.h>
#include <stdint.h>

// MultiHeadAttention: B=2,S=2048,D=1024,H=16,HD=64
// Pipeline: convert(f32->bf16) -> fused QKV GEMM (bf16 MFMA) -> flash attn -> out GEMM (f32 out)

typedef __attribute__((ext_vector_type(8))) short bf16x8;
typedef __attribute__((ext_vector_type(4))) float f32x4;
typedef __attribute__((ext_vector_type(4))) float floatx4;
typedef __attribute__((ext_vector_type(4))) short shortx4;

#define MFMA16(a, b, c) __builtin_amdgcn_mfma_f32_16x16x32_bf16((a), (b), (c), 0, 0, 0)

static __device__ __forceinline__ short f2bf(float f) {
  __hip_bfloat16 h = __float2bfloat16(f);
  return *reinterpret_cast<short*>(&h);
}

static __device__ __forceinline__ float fexp2(float x) {
#if __has_builtin(__builtin_amdgcn_exp2f)
  return __builtin_amdgcn_exp2f(x);
#else
  return exp2f(x);
#endif
}

static __device__ __forceinline__ void gload_lds16(const void* g, void* l) {
  __builtin_amdgcn_global_load_lds(
      (__attribute__((address_space(1))) void*)(void*)g,
      (__attribute__((address_space(3))) void*)l, 16, 0, 0);
}

// ---------------------------------------------------------------------------
// Convert inputs to bf16 workspace + concat biases.
// ---------------------------------------------------------------------------
__global__ void convert_kernel(const float* __restrict__ x,
                               const float* __restrict__ Wq, const float* __restrict__ Wk,
                               const float* __restrict__ Wv, const float* __restrict__ Wo,
                               const float* __restrict__ bq, const float* __restrict__ bk,
                               const float* __restrict__ bv,
                               __hip_bfloat16* __restrict__ xb,
                               __hip_bfloat16* __restrict__ wqkv,
                               __hip_bfloat16* __restrict__ wob,
                               float* __restrict__ bcat) {
  const int NX = (4096 * 1024) / 4;  // x quads
  const int NW = (1024 * 1024) / 4;  // per-weight quads
  const int total = NX + 4 * NW;
  for (long i = (long)blockIdx.x * blockDim.x + threadIdx.x; i < total + 768;
       i += (long)gridDim.x * blockDim.x) {
    if (i < total) {
      const float* src;
      __hip_bfloat16* dst;
      long off;
      if (i < NX)             { src = x;  dst = xb;                       off = i; }
      else if (i < NX + NW)   { src = Wq; dst = wqkv;                     off = i - NX; }
      else if (i < NX + 2*NW) { src = Wk; dst = wqkv + 1024 * 1024;       off = i - NX - NW; }
      else if (i < NX + 3*NW) { src = Wv; dst = wqkv + 2 * 1024 * 1024;   off = i - NX - 2*NW; }
      else                    { src = Wo; dst = wob;                      off = i - NX - 3*NW; }
      floatx4 v = *(const floatx4*)(src + off * 4);
      shortx4 sv;
      sv.x = f2bf(v.x); sv.y = f2bf(v.y); sv.z = f2bf(v.z); sv.w = f2bf(v.w);
      *(shortx4*)(dst + off * 4) = sv;
    } else {
      int j = (int)(i - total);  // 0..767
#pragma unroll
      for (int u = 0; u < 4; ++u) {
        int n = j * 4 + u;
        float b = (n < 1024) ? bq[n] : (n < 2048 ? bk[n - 1024] : bv[n - 2048]);
        bcat[n] = b;
      }
    }
  }
}

// ---------------------------------------------------------------------------
// GEMM: C[M,N] = (A[M,K] @ Bm[N,K]^T + bias) * scale(col)
// 128x128 tile, BK=64, 4 waves (2x2 of 64x64), global_load_lds w16,
// XOR-swizzled LDS via pre-swizzled global source addresses.
// ---------------------------------------------------------------------------
template <bool OUT_BF16>
__global__ __launch_bounds__(256, 2) void gemm_bt(const __hip_bfloat16* __restrict__ A,
                                                  const __hip_bfloat16* __restrict__ Bm,
                                                  const float* __restrict__ bias,
                                                  void* __restrict__ Cout, int M, int N, int K,
                                                  float scale, int scale_limit) {
  __shared__ __hip_bfloat16 As[128 * 64];
  __shared__ __hip_bfloat16 Bs[128 * 64];
  const int tid = threadIdx.x;
  const int lane = tid & 63;
  const int w = tid >> 6;
  const int wm = w >> 1, wn = w & 1;

  // XCD-aware swizzle (gridDim.x % 8 == 0 for all our launches)
  const int nwg = gridDim.x;
  const int bi = blockIdx.x;
  const int wg = (bi & 7) * (nwg >> 3) + (bi >> 3);
  const int MT = M >> 7;
  const int tm = wg % MT, tn = wg / MT;
  const long brow = (long)tm * 128, bcol = (long)tn * 128;

  const int srow = tid >> 3;          // staging row within 32-row pass
  const int scsw = (tid & 7) << 4;    // swizzled col-byte

  f32x4 acc[4][4] = {};

  char* lAs = (char*)As + (tid & 0xC0) * 16;  // wave-uniform base (= w*1024)
  char* lBs = (char*)Bs + (tid & 0xC0) * 16;

  for (int k0 = 0; k0 < K; k0 += 64) {
#pragma unroll
    for (int p = 0; p < 4; ++p) {
      int r = p * 32 + srow;
      int cb = scsw ^ ((r & 7) << 4);  // pre-swizzled global source
      gload_lds16(A + (brow + r) * (long)K + k0 + (cb >> 1), lAs + p * 4096);
      gload_lds16(Bm + (bcol + r) * (long)K + k0 + (cb >> 1), lBs + p * 4096);
    }
    __syncthreads();
#pragma unroll
    for (int ks = 0; ks < 2; ++ks) {
      bf16x8 af[4], bfr[4];
      const int cbase = ks * 64 + ((lane >> 4) << 4);
#pragma unroll
      for (int m = 0; m < 4; ++m) {
        int r = wm * 64 + m * 16 + (lane & 15);
        af[m] = *(const bf16x8*)((const char*)As + r * 128 + (cbase ^ ((r & 7) << 4)));
      }
#pragma unroll
      for (int n = 0; n < 4; ++n) {
        int r = wn * 64 + n * 16 + (lane & 15);
        bfr[n] = *(const bf16x8*)((const char*)Bs + r * 128 + (cbase ^ ((r & 7) << 4)));
      }
#pragma unroll
      for (int m = 0; m < 4; ++m)
#pragma unroll
        for (int n = 0; n < 4; ++n) acc[m][n] = MFMA16(af[m], bfr[n], acc[m][n]);
    }
    __syncthreads();
  }

#pragma unroll
  for (int n = 0; n < 4; ++n) {
    const long col = bcol + wn * 64 + n * 16 + (lane & 15);
    const float bv = bias[col];
    const float sc = (col < scale_limit) ? scale : 1.0f;
#pragma unroll
    for (int m = 0; m < 4; ++m) {
      const long row0 = brow + wm * 64 + m * 16 + ((lane >> 4) << 2);
#pragma unroll
      for (int j = 0; j < 4; ++j) {
        float v = (acc[m][n][j] + bv) * sc;
        if (OUT_BF16)
          ((__hip_bfloat16*)Cout)[(row0 + j) * N + col] = __float2bfloat16(v);
        else
          ((float*)Cout)[(row0 + j) * N + col] = v;
      }
    }
  }
}

// ---------------------------------------------------------------------------
// Flash attention. qkv: [4096, 3072] bf16 (Q|K|V per row, head-major cols of 64).
// Q already scaled by 0.125*log2(e). Output O: [4096, 1024] bf16.
// Grid: 512 = (qtile 16) x (head 16) x (batch 2). 4 waves x 32 q-rows.
// ---------------------------------------------------------------------------
__global__ __launch_bounds__(256, 2) void attn_kernel(const __hip_bfloat16* __restrict__ qkv,
                                                      __hip_bfloat16* __restrict__ O) {
  __shared__ __hip_bfloat16 Ks[128 * 64];   // [kv][64], 128B rows, XOR-swizzled
  __shared__ __hip_bfloat16 Vt[64 * 128];   // [d][kv], 256B rows, XOR-swizzled
  __shared__ __hip_bfloat16 Pl[128 * 128];  // [q][kv], 256B rows, XOR-swizzled

  const int tid = threadIdx.x;
  const int lane = tid & 63;
  const int w = tid >> 6;
  const int bi = blockIdx.x;
  const int qt = bi & 15, hh = (bi >> 4) & 15, bb = bi >> 8;
  const long rowQ0 = (long)bb * 2048 + qt * 128;
  const long rowK0 = (long)bb * 2048;
  const int qcol = hh * 64, kcol = 1024 + hh * 64, vcol = 2048 + hh * 64;

  // Preload Q fragments (this wave's 32 rows), K-dim = d (64) -> 2 k-steps
  bf16x8 qf[2][2];
#pragma unroll
  for (int m = 0; m < 2; ++m)
#pragma unroll
    for (int ks = 0; ks < 2; ++ks) {
      long r = rowQ0 + w * 32 + m * 16 + (lane & 15);
      int c = qcol + ks * 32 + ((lane >> 4) << 3);
      qf[m][ks] = *(const bf16x8*)(qkv + r * 3072 + c);
    }

  f32x4 acc_o[2][4] = {};
  float mrun[8], lrun[8];
#pragma unroll
  for (int i = 0; i < 8; ++i) { mrun[i] = -1e30f; lrun[i] = 0.f; }

  const int srow = tid >> 3;
  const int scsw = (tid & 7) << 4;
  char* lKs = (char*)Ks + (tid & 0xC0) * 16;
  const int vr = tid >> 1;          // kv row this thread stages for V
  const int vc0 = (tid & 1) * 32;   // d base

  for (int t = 0; t < 16; ++t) {
    const long kv0 = (long)t * 128;
    // --- stage K (global_load_lds, pre-swizzled source) ---
#pragma unroll
    for (int p = 0; p < 4; ++p) {
      int r = p * 32 + srow;
      int cb = scsw ^ ((r & 7) << 4);
      gload_lds16(qkv + (rowK0 + kv0 + r) * 3072 + kcol + (cb >> 1), lKs + p * 4096);
    }
    // --- stage V transposed into Vt (register path, swizzled scalar writes) ---
#pragma unroll
    for (int u = 0; u < 4; ++u) {
      bf16x8 v = *(const bf16x8*)(qkv + (rowK0 + kv0 + vr) * 3072 + vcol + vc0 + u * 8);
#pragma unroll
      for (int e = 0; e < 8; ++e) {
        int d = vc0 + u * 8 + e;
        int blk = (vr >> 3) ^ (d & 15);
        *(short*)((char*)Vt + d * 256 + blk * 16 + ((vr & 7) << 1)) = v[e];
      }
    }
    __syncthreads();

    // --- S = Q.K^T (per wave: 32 q-rows x 128 kv-cols) ---
    f32x4 s[2][8] = {};
#pragma unroll
    for (int ks = 0; ks < 2; ++ks) {
      bf16x8 kf[8];
      const int cbase = ks * 64 + ((lane >> 4) << 4);
#pragma unroll
      for (int n = 0; n < 8; ++n) {
        int r = n * 16 + (lane & 15);
        kf[n] = *(const bf16x8*)((const char*)Ks + r * 128 + (cbase ^ ((r & 7) << 4)));
      }
#pragma unroll
      for (int m = 0; m < 2; ++m)
#pragma unroll
        for (int n = 0; n < 8; ++n) s[m][n] = MFMA16(qf[m][ks], kf[n], s[m][n]);
    }

    // --- online softmax (rows spread: lane holds rows (lane>>4)*4+j per 16-blk) ---
    float corr[2][4];
#pragma unroll
    for (int m = 0; m < 2; ++m)
#pragma unroll
      for (int j = 0; j < 4; ++j) {
        const int idx = m * 4 + j;
        float mx = s[m][0][j];
#pragma unroll
        for (int n = 1; n < 8; ++n) mx = fmaxf(mx, s[m][n][j]);
        mx = fmaxf(mx, __shfl_xor(mx, 1));
        mx = fmaxf(mx, __shfl_xor(mx, 2));
        mx = fmaxf(mx, __shfl_xor(mx, 4));
        mx = fmaxf(mx, __shfl_xor(mx, 8));
        float newm = fmaxf(mrun[idx], mx);
        float c = fexp2(mrun[idx] - newm);
        corr[m][j] = c;
        mrun[idx] = newm;
        float rs = 0.f;
#pragma unroll
        for (int n = 0; n < 8; ++n) {
          float p = fexp2(s[m][n][j] - newm);
          s[m][n][j] = p;
          rs += p;
        }
        rs += __shfl_xor(rs, 1);
        rs += __shfl_xor(rs, 2);
        rs += __shfl_xor(rs, 4);
        rs += __shfl_xor(rs, 8);
        lrun[idx] = lrun[idx] * c + rs;
      }
#pragma unroll
    for (int m = 0; m < 2; ++m)
#pragma unroll
      for (int n = 0; n < 4; ++n)
#pragma unroll
        for (int j = 0; j < 4; ++j) acc_o[m][n][j] *= corr[m][j];

    // --- write P to LDS (bf16, swizzled) ---
#pragma unroll
    for (int m = 0; m < 2; ++m)
#pragma unroll
      for (int n = 0; n < 8; ++n)
#pragma unroll
        for (int j = 0; j < 4; ++j) {
          int rp = w * 32 + m * 16 + ((lane >> 4) << 2) + j;
          int cbyte = n * 32 + ((lane & 15) << 1);
          int blk = (cbyte >> 4) ^ (rp & 15);
          *(short*)((char*)Pl + rp * 256 + blk * 16 + (cbyte & 15)) = f2bf(s[m][n][j]);
        }
    __syncthreads();

    // --- O += P.V (contraction over kv=128 -> 4 k-steps) ---
#pragma unroll
    for (int ks = 0; ks < 4; ++ks) {
      bf16x8 pf[2], vf[4];
#pragma unroll
      for (int m = 0; m < 2; ++m) {
        int rp = w * 32 + m * 16 + (lane & 15);
        int blk = (ks * 4 + (lane >> 4)) ^ (rp & 15);
        pf[m] = *(const bf16x8*)((const char*)Pl + rp * 256 + blk * 16);
      }
#pragma unroll
      for (int n = 0; n < 4; ++n) {
        int d = n * 16 + (lane & 15);
        int blk = (ks * 4 + (lane >> 4)) ^ (d & 15);
        vf[n] = *(const bf16x8*)((const char*)Vt + d * 256 + blk * 16);
      }
#pragma unroll
      for (int m = 0; m < 2; ++m)
#pragma unroll
        for (int n = 0; n < 4; ++n) acc_o[m][n] = MFMA16(pf[m], vf[n], acc_o[m][n]);
    }
    __syncthreads();
  }

  // --- epilogue: O /= l, store bf16 ---
#pragma unroll
  for (int m = 0; m < 2; ++m)
#pragma unroll
    for (int j = 0; j < 4; ++j) {
      const int idx = m * 4 + j;
      const float inv = 1.0f / lrun[idx];
      const long r = rowQ0 + w * 32 + m * 16 + ((lane >> 4) << 2) + j;
#pragma unroll
      for (int n = 0; n < 4; ++n) {
        int d = n * 16 + (lane & 15);
        O[r * 1024 + qcol + d] = __float2bfloat16(acc_o[m][n][j] * inv);
      }
    }
}

// ---------------------------------------------------------------------------
extern "C" void kernel_launch(void* const* d_in, const int* in_sizes, int n_in,
                              void* d_out, int out_size, void* d_ws, size_t ws_size,
                              hipStream_t stream) {
  const float* x  = (const float*)d_in[0];
  const float* Wq = (const float*)d_in[1];
  const float* bq = (const float*)d_in[2];
  const float* Wk = (const float*)d_in[3];
  const float* bk = (const float*)d_in[4];
  const float* Wv = (const float*)d_in[5];
  const float* bv = (const float*)d_in[6];
  const float* Wo = (const float*)d_in[7];
  const float* bo = (const float*)d_in[8];

  __hip_bfloat16* ws = (__hip_bfloat16*)d_ws;
  __hip_bfloat16* xb   = ws;
  __hip_bfloat16* wqkv = xb + (size_t)4096 * 1024;
  __hip_bfloat16* wob  = wqkv + (size_t)3072 * 1024;
  __hip_bfloat16* qkvb = wob + (size_t)1024 * 1024;
  __hip_bfloat16* ob   = qkvb + (size_t)4096 * 3072;
  float* bcat = (float*)(ob + (size_t)4096 * 1024);

  // 0.125 (1/sqrt(HD)) * log2(e), folded into Q so attention uses exp2 directly
  const float qscale = 0.18033688011112042f;

  convert_kernel<<<dim3(2048), dim3(256), 0, stream>>>(x, Wq, Wk, Wv, Wo, bq, bk, bv,
                                                       xb, wqkv, wob, bcat);
  gemm_bt<true><<<dim3(768), dim3(256), 0, stream>>>(xb, wqkv, bcat, (void*)qkvb,
                                                     4096, 3072, 1024, qscale, 1024);
  attn_kernel<<<dim3(512), dim3(256), 0, stream>>>(qkvb, ob);
  gemm_bt<false><<<dim3(256), dim3(256), 0, stream>>>(ob, wob, bo, d_out,
                                                      4096, 1024, 1024, 1.0f, 0);
}

// Round 6
// 198.581 us; speedup vs baseline: 1.1959x; 1.1959x over previous
//
#include <hip/hip_runtime.h>
#include <hip/hip_bf16.h>
#include <stdint.h>

// MultiHeadAttention: B=2,S=2048,D=1024,H=16,HD=64
// Pipeline: convert(f32->bf16) -> fused QKV GEMM (bf16 MFMA) -> flash attn -> out GEMM (f32 out)
// Attn: swapped-QK^T (St = mfma(K,Q)) so P is lane-local; P fed to PV entirely
// in registers via a kv-axis permutation shared with V^T's LDS layout.
// P packing uses a bit-exact manual bf16 pack (NOT v_cvt_pk_bf16_f32 asm).

typedef __attribute__((ext_vector_type(8))) short bf16x8;
typedef __attribute__((ext_vector_type(4))) float f32x4;
typedef __attribute__((ext_vector_type(4))) float floatx4;
typedef __attribute__((ext_vector_type(4))) short shortx4;

#define MFMA16(a, b, c) __builtin_amdgcn_mfma_f32_16x16x32_bf16((a), (b), (c), 0, 0, 0)

static __device__ __forceinline__ short f2bf(float f) {
  __hip_bfloat16 h = __float2bfloat16(f);
  return *reinterpret_cast<short*>(&h);
}

// Bit-exact pack: lo 16 bits = bf16(a) (element 0), hi 16 bits = bf16(b).
static __device__ __forceinline__ uint32_t pack_bf16(float a, float b) {
  return (uint32_t)(uint16_t)f2bf(a) | ((uint32_t)(uint16_t)f2bf(b) << 16);
}

static __device__ __forceinline__ float fexp2(float x) {
#if __has_builtin(__builtin_amdgcn_exp2f)
  return __builtin_amdgcn_exp2f(x);
#else
  return exp2f(x);
#endif
}

static __device__ __forceinline__ void gload_lds16(const void* g, void* l) {
  __builtin_amdgcn_global_load_lds(
      (__attribute__((address_space(1))) void*)(void*)g,
      (__attribute__((address_space(3))) void*)l, 16, 0, 0);
}

// ---------------------------------------------------------------------------
// Convert inputs to bf16 workspace + concat biases.
// ---------------------------------------------------------------------------
__global__ void convert_kernel(const float* __restrict__ x,
                               const float* __restrict__ Wq, const float* __restrict__ Wk,
                               const float* __restrict__ Wv, const float* __restrict__ Wo,
                               const float* __restrict__ bq, const float* __restrict__ bk,
                               const float* __restrict__ bv,
                               __hip_bfloat16* __restrict__ xb,
                               __hip_bfloat16* __restrict__ wqkv,
                               __hip_bfloat16* __restrict__ wob,
                               float* __restrict__ bcat) {
  const int NX = (4096 * 1024) / 4;  // x quads
  const int NW = (1024 * 1024) / 4;  // per-weight quads
  const int total = NX + 4 * NW;
  for (long i = (long)blockIdx.x * blockDim.x + threadIdx.x; i < total + 768;
       i += (long)gridDim.x * blockDim.x) {
    if (i < total) {
      const float* src;
      __hip_bfloat16* dst;
      long off;
      if (i < NX)             { src = x;  dst = xb;                       off = i; }
      else if (i < NX + NW)   { src = Wq; dst = wqkv;                     off = i - NX; }
      else if (i < NX + 2*NW) { src = Wk; dst = wqkv + 1024 * 1024;       off = i - NX - NW; }
      else if (i < NX + 3*NW) { src = Wv; dst = wqkv + 2 * 1024 * 1024;   off = i - NX - 2*NW; }
      else                    { src = Wo; dst = wob;                      off = i - NX - 3*NW; }
      floatx4 v = *(const floatx4*)(src + off * 4);
      shortx4 sv;
      sv.x = f2bf(v.x); sv.y = f2bf(v.y); sv.z = f2bf(v.z); sv.w = f2bf(v.w);
      *(shortx4*)(dst + off * 4) = sv;
    } else {
      int j = (int)(i - total);  // 0..767
#pragma unroll
      for (int u = 0; u < 4; ++u) {
        int n = j * 4 + u;
        float b = (n < 1024) ? bq[n] : (n < 2048 ? bk[n - 1024] : bv[n - 2048]);
        bcat[n] = b;
      }
    }
  }
}

// ---------------------------------------------------------------------------
// GEMM: C[M,N] = (A[M,K] @ Bm[N,K]^T + bias) * scale(col)
// 128x128 tile, BK=64, 4 waves (2x2 of 64x64), global_load_lds w16,
// XOR-swizzled LDS via pre-swizzled global source addresses.
// ---------------------------------------------------------------------------
template <bool OUT_BF16>
__global__ __launch_bounds__(256, 2) void gemm_bt(const __hip_bfloat16* __restrict__ A,
                                                  const __hip_bfloat16* __restrict__ Bm,
                                                  const float* __restrict__ bias,
                                                  void* __restrict__ Cout, int M, int N, int K,
                                                  float scale, int scale_limit) {
  __shared__ __hip_bfloat16 As[128 * 64];
  __shared__ __hip_bfloat16 Bs[128 * 64];
  const int tid = threadIdx.x;
  const int lane = tid & 63;
  const int w = tid >> 6;
  const int wm = w >> 1, wn = w & 1;

  // XCD-aware swizzle (gridDim.x % 8 == 0 for all our launches)
  const int nwg = gridDim.x;
  const int bi = blockIdx.x;
  const int wg = (bi & 7) * (nwg >> 3) + (bi >> 3);
  const int MT = M >> 7;
  const int tm = wg % MT, tn = wg / MT;
  const long brow = (long)tm * 128, bcol = (long)tn * 128;

  const int srow = tid >> 3;          // staging row within 32-row pass
  const int scsw = (tid & 7) << 4;    // swizzled col-byte

  f32x4 acc[4][4] = {};

  char* lAs = (char*)As + (tid & 0xC0) * 16;  // wave-uniform base (= w*1024)
  char* lBs = (char*)Bs + (tid & 0xC0) * 16;

  for (int k0 = 0; k0 < K; k0 += 64) {
#pragma unroll
    for (int p = 0; p < 4; ++p) {
      int r = p * 32 + srow;
      int cb = scsw ^ ((r & 7) << 4);  // pre-swizzled global source
      gload_lds16(A + (brow + r) * (long)K + k0 + (cb >> 1), lAs + p * 4096);
      gload_lds16(Bm + (bcol + r) * (long)K + k0 + (cb >> 1), lBs + p * 4096);
    }
    __syncthreads();
#pragma unroll
    for (int ks = 0; ks < 2; ++ks) {
      bf16x8 af[4], bfr[4];
      const int cbase = ks * 64 + ((lane >> 4) << 4);
#pragma unroll
      for (int m = 0; m < 4; ++m) {
        int r = wm * 64 + m * 16 + (lane & 15);
        af[m] = *(const bf16x8*)((const char*)As + r * 128 + (cbase ^ ((r & 7) << 4)));
      }
#pragma unroll
      for (int n = 0; n < 4; ++n) {
        int r = wn * 64 + n * 16 + (lane & 15);
        bfr[n] = *(const bf16x8*)((const char*)Bs + r * 128 + (cbase ^ ((r & 7) << 4)));
      }
#pragma unroll
      for (int m = 0; m < 4; ++m)
#pragma unroll
        for (int n = 0; n < 4; ++n) acc[m][n] = MFMA16(af[m], bfr[n], acc[m][n]);
    }
    __syncthreads();
  }

#pragma unroll
  for (int n = 0; n < 4; ++n) {
    const long col = bcol + wn * 64 + n * 16 + (lane & 15);
    const float bv = bias[col];
    const float sc = (col < scale_limit) ? scale : 1.0f;
#pragma unroll
    for (int m = 0; m < 4; ++m) {
      const long row0 = brow + wm * 64 + m * 16 + ((lane >> 4) << 2);
#pragma unroll
      for (int j = 0; j < 4; ++j) {
        float v = (acc[m][n][j] + bv) * sc;
        if (OUT_BF16)
          ((__hip_bfloat16*)Cout)[(row0 + j) * N + col] = __float2bfloat16(v);
        else
          ((float*)Cout)[(row0 + j) * N + col] = v;
      }
    }
  }
}

// ---------------------------------------------------------------------------
// Flash attention, swapped-QK^T / in-register-P version.
// qkv: [4096, 3072] bf16 (Q|K|V per row, head-major cols of 64).
// Q pre-scaled by 0.125*log2(e). O: [4096, 1024] bf16.
// Grid: 512 = (qtile 16) x (head 16) x (batch 2). 4 waves x 32 q-rows.
//
// kv-axis permutation phi(kv) = 32*(n>>1) + 8*g + 4*(n&1) + j
//   (kv = 16n + 4g + j). P's A-fragment slot order and Vt's column order
// both use phi, so the contraction stays consistent with zero cross-lane ops.
// ---------------------------------------------------------------------------
__global__ __launch_bounds__(256, 2) void attn_kernel(const __hip_bfloat16* __restrict__ qkv,
                                                      __hip_bfloat16* __restrict__ O) {
  __shared__ __hip_bfloat16 Ks[128 * 64];   // [kv][64], 128B rows, XOR-swizzled
  __shared__ __hip_bfloat16 Vt[64 * 128];   // [d][phi(kv)], 256B rows, XOR-swizzled

  const int tid = threadIdx.x;
  const int lane = tid & 63;
  const int w = tid >> 6;
  const int g = lane >> 4;     // 16-lane group
  const int t = lane & 15;     // lane-in-group: q-row (softmax) / d-col (PV C)
  const int bi = blockIdx.x;
  const int qt = bi & 15, hh = (bi >> 4) & 15, bb = bi >> 8;
  const long rowQ0 = (long)bb * 2048 + qt * 128;
  const long rowK0 = (long)bb * 2048;
  const int qcol = hh * 64, kcol = 1024 + hh * 64, vcol = 2048 + hh * 64;

  // Q fragments (B-operand of swapped QK): col=q=t, k-chunk = ks*32 + g*8
  bf16x8 qf[2][2];
#pragma unroll
  for (int m = 0; m < 2; ++m)
#pragma unroll
    for (int ks = 0; ks < 2; ++ks) {
      long r = rowQ0 + w * 32 + m * 16 + t;
      int c = qcol + ks * 32 + g * 8;
      qf[m][ks] = *(const bf16x8*)(qkv + r * 3072 + c);
    }

  f32x4 acc_o[2][4] = {};
  float mrun[2] = {-1e30f, -1e30f}, lrun[2] = {0.f, 0.f};
  uint32_t cpk[2][8][2];  // packed bf16 P-pairs: [m][n][h], pair kv = 16n+4g+2h

  // broadcast source base: lane (g, t'=g*4+j) within same group
  const int sb = (lane & 48) | ((lane & 48) >> 2);

  const int srow = tid >> 3;
  const int scsw = (tid & 7) << 4;
  char* lKs = (char*)Ks + (tid & 0xC0) * 16;
  const int vr = tid >> 1;          // kv row this thread stages for V
  const int vc0 = (tid & 1) * 32;   // d base
  // phi decomposition for the staged kv row (constant per thread)
  const int vphib = 4 * (vr >> 5) + ((vr >> 2) & 3);       // 16B block idx
  const int vinb = ((vr >> 4) & 1) * 8 + (vr & 3) * 2;     // byte within block

  for (int tt = 0; tt < 16; ++tt) {
    const long kv0 = (long)tt * 128;
    // --- stage K (global_load_lds, pre-swizzled source) ---
#pragma unroll
    for (int p = 0; p < 4; ++p) {
      int r = p * 32 + srow;
      int cb = scsw ^ ((r & 7) << 4);
      gload_lds16(qkv + (rowK0 + kv0 + r) * 3072 + kcol + (cb >> 1), lKs + p * 4096);
    }
    // --- stage V transposed into Vt at phi-columns (swizzled scalar writes) ---
#pragma unroll
    for (int u = 0; u < 4; ++u) {
      bf16x8 v = *(const bf16x8*)(qkv + (rowK0 + kv0 + vr) * 3072 + vcol + vc0 + u * 8);
#pragma unroll
      for (int e = 0; e < 8; ++e) {
        int d = vc0 + u * 8 + e;
        *(short*)((char*)Vt + d * 256 + ((vphib ^ (d & 15)) << 4) + vinb) = v[e];
      }
    }
    __syncthreads();

    // --- per q-tile m: St = K.Q^T, softmax, pack P ---
#pragma unroll
    for (int m = 0; m < 2; ++m) {
      f32x4 s[8] = {};  // s[n][j] = S[q=m*16+t][kv=16n+4g+j]
#pragma unroll
      for (int ks = 0; ks < 2; ++ks) {
        const int cbase = ks * 64 + g * 16;
#pragma unroll
        for (int n = 0; n < 8; ++n) {
          int r = n * 16 + t;
          bf16x8 kf = *(const bf16x8*)((const char*)Ks + r * 128 + (cbase ^ ((r & 7) << 4)));
          s[n] = MFMA16(kf, qf[m][ks], s[n]);
        }
      }
      // row max (lane-local 32 values + 2 shuffles)
      float mx = s[0][0];
#pragma unroll
      for (int n = 0; n < 8; ++n)
#pragma unroll
        for (int j = 0; j < 4; ++j) mx = fmaxf(mx, s[n][j]);
      mx = fmaxf(mx, __shfl_xor(mx, 16));
      mx = fmaxf(mx, __shfl_xor(mx, 32));
      const float newm = fmaxf(mrun[m], mx);
      const float corr = fexp2(mrun[m] - newm);
      mrun[m] = newm;
      float rs = 0.f;
#pragma unroll
      for (int n = 0; n < 8; ++n)
#pragma unroll
        for (int j = 0; j < 4; ++j) {
          float p = fexp2(s[n][j] - newm);
          s[n][j] = p;
          rs += p;
        }
      rs += __shfl_xor(rs, 16);
      rs += __shfl_xor(rs, 32);
      lrun[m] = lrun[m] * corr + rs;
      // rescale acc_o[m]: corr lives at lane (g, t=g*4+j) -> broadcast per row j
#pragma unroll
      for (int j = 0; j < 4; ++j) {
        float cj = __shfl(corr, sb | j);
#pragma unroll
        for (int nd = 0; nd < 4; ++nd) acc_o[m][nd][j] *= cj;
      }
      // pack P into bf16 pairs (kv pair = 16n+4g+{2h,2h+1}); bit-exact manual pack
#pragma unroll
      for (int n = 0; n < 8; ++n) {
        cpk[m][n][0] = pack_bf16(s[n][0], s[n][1]);
        cpk[m][n][1] = pack_bf16(s[n][2], s[n][3]);
      }
    }

    // --- O += P.V over phi-ordered kv (4 k-steps of 32) ---
#pragma unroll
    for (int ks = 0; ks < 4; ++ks) {
      bf16x8 vf[4];
#pragma unroll
      for (int nd = 0; nd < 4; ++nd) {
        int d = nd * 16 + t;
        vf[nd] = *(const bf16x8*)((const char*)Vt + d * 256 + (((4 * ks + g) ^ t) << 4));
      }
#pragma unroll
      for (int m = 0; m < 2; ++m) {
        union { bf16x8 v; uint32_t u[4]; } au;
        au.u[0] = cpk[m][2 * ks][0];
        au.u[1] = cpk[m][2 * ks][1];
        au.u[2] = cpk[m][2 * ks + 1][0];
        au.u[3] = cpk[m][2 * ks + 1][1];
#pragma unroll
        for (int nd = 0; nd < 4; ++nd) acc_o[m][nd] = MFMA16(au.v, vf[nd], acc_o[m][nd]);
      }
    }
    __syncthreads();
  }

  // --- epilogue: O /= l (broadcast per row), store bf16 ---
#pragma unroll
  for (int m = 0; m < 2; ++m) {
    const float inv = 1.0f / lrun[m];
#pragma unroll
    for (int j = 0; j < 4; ++j) {
      const float ij = __shfl(inv, sb | j);
      const long r = rowQ0 + w * 32 + m * 16 + g * 4 + j;
#pragma unroll
      for (int nd = 0; nd < 4; ++nd) {
        O[r * 1024 + qcol + nd * 16 + t] = __float2bfloat16(acc_o[m][nd][j] * ij);
      }
    }
  }
}

// ---------------------------------------------------------------------------
extern "C" void kernel_launch(void* const* d_in, const int* in_sizes, int n_in,
                              void* d_out, int out_size, void* d_ws, size_t ws_size,
                              hipStream_t stream) {
  const float* x  = (const float*)d_in[0];
  const float* Wq = (const float*)d_in[1];
  const float* bq = (const float*)d_in[2];
  const float* Wk = (const float*)d_in[3];
  const float* bk = (const float*)d_in[4];
  const float* Wv = (const float*)d_in[5];
  const float* bv = (const float*)d_in[6];
  const float* Wo = (const float*)d_in[7];
  const float* bo = (const float*)d_in[8];

  __hip_bfloat16* ws = (__hip_bfloat16*)d_ws;
  __hip_bfloat16* xb   = ws;
  __hip_bfloat16* wqkv = xb + (size_t)4096 * 1024;
  __hip_bfloat16* wob  = wqkv + (size_t)3072 * 1024;
  __hip_bfloat16* qkvb = wob + (size_t)1024 * 1024;
  __hip_bfloat16* ob   = qkvb + (size_t)4096 * 3072;
  float* bcat = (float*)(ob + (size_t)4096 * 1024);

  // 0.125 (1/sqrt(HD)) * log2(e), folded into Q so attention uses exp2 directly
  const float qscale = 0.18033688011112042f;

  convert_kernel<<<dim3(2048), dim3(256), 0, stream>>>(x, Wq, Wk, Wv, Wo, bq, bk, bv,
                                                       xb, wqkv, wob, bcat);
  gemm_bt<true><<<dim3(768), dim3(256), 0, stream>>>(xb, wqkv, bcat, (void*)qkvb,
                                                     4096, 3072, 1024, qscale, 1024);
  attn_kernel<<<dim3(512), dim3(256), 0, stream>>>(qkvb, ob);
  gemm_bt<false><<<dim3(256), dim3(256), 0, stream>>>(ob, wob, bo, d_out,
                                                      4096, 1024, 1024, 1.0f, 0);
}